// Round 13
// baseline (52.334 us; speedup 1.0000x reference)
//
#include <hip/hip_runtime.h>
#include <hip/hip_bf16.h>
#include <math.h>

#define SIDE 48
#define PPOS (SIDE*SIDE)
#define NBATCH 2
#define NHYP 4
#define FD 32
#define RD 8
#define NJ 104
#define NBP (NBATCH*PPOS)       // 4608
#define NOUT (NBP*NHYP)         // 18432
#define THREADS 512
#define NROWS 576
#define NBLK (NBP/4)            // 1152 (2x2 tiles: 24x24x2)
// d_ws dword offsets
#define WS_SR   16              // 9 f32
#define WS_SQR  28              // 9 f32
#define WS_SC   40              // 3 f32
#define WS_RC   64              // 9*128 f32
#define WS_S    1216            // 128 f32
#define WS_T    1344            // 128 f32 (pre-scaled: (T+b1)*32 + 512.5)
#define WS_W2   1472            // 128 f32
#define WS_WBF  1600            // 2048 dw
#define WS_WAF  3648            // 2048 dw
#define WS_PART 5696            // 3*NBLK f32

typedef __attribute__((ext_vector_type(8))) short short8;
typedef __attribute__((ext_vector_type(4))) float f32x4;
union U8 { uint4 u4; short8 s8; };

__device__ __forceinline__ float bflo(unsigned u) { return __uint_as_float(u << 16); }
__device__ __forceinline__ float bfhi(unsigned u) { return __uint_as_float(u & 0xffff0000u); }
__device__ __forceinline__ unsigned packbf2(float a, float b) {
    unsigned ua = __float_as_uint(a), ub = __float_as_uint(b);
    unsigned ra = (ua + 0x7fffu + ((ua >> 16) & 1u)) >> 16;
    unsigned rb = (ub + 0x7fffu + ((ub >> 16) & 1u)) & 0xffff0000u;
    return ra | rb;
}
__device__ __forceinline__ float softplusf(float v) {
    return fmaxf(v, 0.f) + log1pf(expf(-fabsf(v)));
}

#define W1X(kk, j) ((j) < 64 ? sup_w1[(kk)*64 + (j)] : con_w1[(kk)*64 + (j) - 64])

// ---------------- pre-kernel: fold weights once (11 blocks) ----------------
__global__ __launch_bounds__(512) void eml_fold(
    const float* __restrict__ rel, const float* __restrict__ ln_w, const float* __restrict__ ln_b,
    const float* __restrict__ sup_w1, const float* __restrict__ sup_b1,
    const float* __restrict__ sup_w2, const float* __restrict__ sup_b2,
    const float* __restrict__ con_w1, const float* __restrict__ con_b1,
    const float* __restrict__ con_w2, const float* __restrict__ con_b2,
    const float* __restrict__ eml_bias, float* __restrict__ ws)
{
    const int tid = threadIdx.x;
    const int bid = blockIdx.x;
    unsigned* wsd = reinterpret_cast<unsigned*>(ws);
    __shared__ float pS[4][128], pT[4][128];

    if (bid < 8) {
        // B-fragments: lane l holds W^T[col][k] pairs, k0=(l>>4)*8+2j
        int u = bid*512 + tid;
        int sel = u >> 11, v2 = u & 2047;
        int n = v2 >> 8, l = (v2 >> 2) & 63, j = v2 & 3;
        int k0 = (l >> 4)*8 + 2*j, col = n*16 + (l & 15);
        float lo, hi;
        if (sel == 0) {   // Wb (src)
            lo = ln_w[32+k0]*W1X(32+k0,col)     - ln_w[64+k0]*W1X(64+k0,col);
            hi = ln_w[32+k0+1]*W1X(32+k0+1,col) - ln_w[64+k0+1]*W1X(64+k0+1,col);
        } else {          // Wa (tgt)
            lo = ln_w[k0]*W1X(k0,col)     + ln_w[64+k0]*W1X(64+k0,col);
            hi = ln_w[k0+1]*W1X(k0+1,col) + ln_w[64+k0+1]*W1X(64+k0+1,col);
        }
        wsd[(sel ? WS_WAF : WS_WBF) + v2] = packbf2(lo, hi);
    } else if (bid == 8) {
        #pragma unroll
        for (int u0 = 0; u0 < 2; ++u0) {
            int u = u0*512 + tid;               // rc entries 0..1023
            int k = u >> 7, j = u & 127;
            float a = 0.f;
            #pragma unroll
            for (int i = 0; i < 8; ++i) a += rel[k*8+i] * ln_w[96+i] * W1X(96+i, j);
            ws[WS_RC + u] = a;
        }
    } else if (bid == 9) {
        if (tid < 128) {
            int u = 1024 + tid;                 // rc entries 1024..1151
            int k = u >> 7, j = u & 127;
            float a = 0.f;
            #pragma unroll
            for (int i = 0; i < 8; ++i) a += rel[k*8+i] * ln_w[96+i] * W1X(96+i, j);
            ws[WS_RC + u] = a;
        } else if (tid < 137) {
            int kk = tid - 128;
            float s = 0.f, sq = 0.f;
            #pragma unroll
            for (int i = 0; i < 8; ++i) { float v = rel[kk*8+i]; s += v; sq += v*v; }
            ws[WS_SR+kk] = s; ws[WS_SQR+kk] = sq;
        } else if (tid == 140) {
            ws[WS_SC] = sup_b2[0]; ws[WS_SC+1] = con_b2[0]; ws[WS_SC+2] = eml_bias[0];
        }
    } else {
        // S/T/W2: 4-way split over k
        int col = tid & 127, seg = tid >> 7;
        float S = 0.f, T = 0.f;
        for (int kk = seg*26; kk < seg*26 + 26; ++kk) {
            float w = W1X(kk, col);
            S += ln_w[kk]*w; T += ln_b[kk]*w;
        }
        pS[seg][col] = S; pT[seg][col] = T;
        __syncthreads();
        if (tid < 128) {
            float Tt = pT[0][tid] + pT[1][tid] + pT[2][tid] + pT[3][tid]
                       + (tid < 64 ? sup_b1[tid] : con_b1[tid-64]);
            ws[WS_S + tid]  = pS[0][tid] + pS[1][tid] + pS[2][tid] + pS[3][tid];
            ws[WS_T + tid]  = Tt * 32.f + 512.5f;     // pre-scaled for LUT quantize
            ws[WS_W2 + tid] = (tid < 64 ? sup_w2[tid] : con_w2[tid-64]);
        }
    }
}

// ---------------- main kernel: one 2x2 position tile per block ----------------
__global__ __launch_bounds__(THREADS, 8) void eml_main(
    const float* __restrict__ hs, const float* __restrict__ act_in,
    const float* __restrict__ drive, const float* __restrict__ resist,
    float* __restrict__ out, const float* __restrict__ cst,
    float* __restrict__ part)
{
    __shared__ __align__(16) unsigned sB[64*68];    // 17408 B src@Wb bf16-pair
    __shared__ __align__(16) unsigned sAp[16*68];   // 4352 B  tgt@Wa bf16-pair
    __shared__ union __align__(16) UU {
        __hip_bfloat16 snb[64*40];                  // 5120 B (dead after stage 2)
        unsigned svcv[NROWS];                       // 2304 B (stage 3-4)
    } u;
    __shared__ __align__(16) float sdot[64*16];     // 4096 B [srow][cidx]
    __shared__ __align__(16) float sgelu[1024];     // 4096 B exact-GELU LUT, h=1/32
    __shared__ float sact[64], sSt[64], sSq[64];    // 768 B
    __shared__ float sSr[9], sSqr[9];               // 72 B

    const int tid = threadIdx.x;
    const int blk = blockIdx.x;
    const int b   = blk / 576;
    const int rm  = blk % 576;
    const int y0  = (rm / 24) * 2;
    const int x0  = (rm % 24) * 2;

    // ---- stage 0: GELU LUT ----
    #pragma unroll
    for (int i = tid; i < 1024; i += THREADS) {
        float x = (float)(i - 512) * 0.03125f;
        sgelu[i] = 0.5f * x * (1.0f + erff(x * 0.70710678118654752f));
    }

    // ---- stage 1: 64 halo vectors (4x4 positions x 4 hyp) ----
    const int vec = tid >> 3, q = tid & 7;       // 64 vecs x 8 threads
    const int nb1 = vec >> 2, h1 = vec & 3;
    const int yy = y0 + (nb1 >> 2) - 1, xx = x0 + (nb1 & 3) - 1;
    const bool vld = (yy >= 0) && (yy < SIDE) && (xx >= 0) && (xx < SIDE);
    const int npos = b*PPOS + yy*SIDE + xx;
    float4 v = make_float4(0.f, 0.f, 0.f, 0.f);
    if (vld) v = *reinterpret_cast<const float4*>(&hs[((size_t)npos*NHYP + h1)*FD + q*4]);
    {
        unsigned* drow = reinterpret_cast<unsigned*>(&u.snb[vec*40]);
        drow[q*2]   = packbf2(v.x, v.y);
        drow[q*2+1] = packbf2(v.z, v.w);
        float s  = v.x + v.y + v.z + v.w;
        float sq = v.x*v.x + v.y*v.y + v.z*v.z + v.w*v.w;
        s += __shfl_xor(s, 1); sq += __shfl_xor(sq, 1);
        s += __shfl_xor(s, 2); sq += __shfl_xor(sq, 2);
        s += __shfl_xor(s, 4); sq += __shfl_xor(sq, 4);
        if (q == 0) {
            sSt[vec] = s; sSq[vec] = sq;
            sact[vec] = vld ? act_in[npos*NHYP + h1] : 0.f;
        }
    }
    if (tid < 9) { sSr[tid] = cst[WS_SR+tid]; sSqr[tid] = cst[WS_SQR+tid]; }
    __syncthreads();

    // ---- stage 2: MFMA GEMMs (8 waves; G3 on waves 0-3) ----
    {
        const int wv = tid >> 6, lane = tid & 63;
        const int fr = lane & 15, fq = lane >> 4;
        const char* snbB = reinterpret_cast<const char*>(u.snb);
        U8 bB, bA;
        bB.u4 = reinterpret_cast<const uint4*>(cst + WS_WBF)[wv*64 + lane];
        bA.u4 = reinterpret_cast<const uint4*>(cst + WS_WAF)[wv*64 + lane];
        // G1: src (64 rows) @ Wb -> sB bf16-pair
        #pragma unroll
        for (int m = 0; m < 4; ++m) {
            U8 a; a.u4 = *reinterpret_cast<const uint4*>(snbB + (m*16 + fr)*80 + fq*16);
            f32x4 acc = {0.f, 0.f, 0.f, 0.f};
            acc = __builtin_amdgcn_mfma_f32_16x16x32_bf16(a.s8, bB.s8, acc, 0, 0, 0);
            #pragma unroll
            for (int j = 0; j < 4; ++j) {
                float o = __shfl_xor(acc[j], 1);
                if (!(lane & 1))
                    sB[(m*16 + fq*4 + j)*68 + wv*8 + (fr >> 1)] = packbf2(acc[j], o);
            }
        }
        // G2: tgt (16 center rows: snb 20-27, 36-43) @ Wa -> sAp bf16-pair
        const int trow = (fr < 8) ? (20 + fr) : (28 + fr);
        U8 at; at.u4 = *reinterpret_cast<const uint4*>(snbB + trow*80 + fq*16);
        {
            f32x4 acc = {0.f, 0.f, 0.f, 0.f};
            acc = __builtin_amdgcn_mfma_f32_16x16x32_bf16(at.s8, bA.s8, acc, 0, 0, 0);
            #pragma unroll
            for (int j = 0; j < 4; ++j) {
                float o = __shfl_xor(acc[j], 1);
                if (!(lane & 1))
                    sAp[(fq*4 + j)*68 + wv*8 + (fr >> 1)] = packbf2(acc[j], o);
            }
        }
        // G3: dot[srow][cidx] = tgt @ src^T (waves 0-3, n-tile = wv)
        if (wv < 4) {
            U8 s2; s2.u4 = *reinterpret_cast<const uint4*>(snbB + (wv*16 + fr)*80 + fq*16);
            f32x4 acc = {0.f, 0.f, 0.f, 0.f};
            acc = __builtin_amdgcn_mfma_f32_16x16x32_bf16(at.s8, s2.s8, acc, 0, 0, 0);
            *reinterpret_cast<f32x4*>(&sdot[(wv*16 + fr)*16 + fq*4]) = acc;
        }
    }
    __syncthreads();

    // ---- stage 3: per-row epilogue (both a,b packed bf16; LUT; no clamp) ----
    for (int ri = tid; ri < NROWS; ri += THREADS) {
        const int pos = ri / 144, r = ri % 144;
        const int hh = r / 36, s = r % 36, k = s >> 2, h2 = s & 3;
        const int nbr  = ((pos >> 1) + k/3)*4 + ((pos & 1) + k%3);
        const int srow = nbr*4 + h2;
        const float gate = sact[srow];
        float svv = 0.f, cvv = 0.f;
        if (gate > 0.f) {
            const int cidx = pos*4 + hh;
            const int crow = (pos < 2 ? 20 : 28) + cidx;
            const float dot = sdot[srow*16 + cidx];
            const float mu   = (2.f*sSt[crow] + sSr[k]) * (1.f/NJ);
            const float ssum = 2.f*sSq[crow] + 2.f*sSq[srow] - 2.f*dot + sSqr[k];
            const float rinv = rsqrtf(ssum*(1.f/NJ) - mu*mu + 1e-5f);
            const float r32  = rinv * 32.f;
            const float b32  = -mu * r32;
            const uint4* aR  = reinterpret_cast<const uint4*>(&sAp[cidx*68]);
            const uint4* bR  = reinterpret_cast<const uint4*>(&sB[srow*68]);
            const float4* c4 = reinterpret_cast<const float4*>(cst + WS_RC + k*128);
            float outs = 0.f, outc = 0.f;
            #pragma unroll 2
            for (int jq = 0; jq < 16; ++jq) {
                uint4 ua = aR[jq];
                uint4 ub = bR[jq];
                float4 c0 = c4[jq*2], c1 = c4[jq*2+1];
                float accv = 0.f;
                #define ACC1(AW, BW, CV, EXT, J) { \
                    float d  = (EXT(AW) + EXT(BW)) + (CV); \
                    float qv = fmaf(r32, d, fmaf(b32, cst[WS_S + jq*8 + (J)], cst[WS_T + jq*8 + (J)])); \
                    float g  = sgelu[(unsigned)qv]; \
                    accv = fmaf(g, cst[WS_W2 + jq*8 + (J)], accv); }
                ACC1(ua.x, ub.x, c0.x, bflo, 0)
                ACC1(ua.x, ub.x, c0.y, bfhi, 1)
                ACC1(ua.y, ub.y, c0.z, bflo, 2)
                ACC1(ua.y, ub.y, c0.w, bfhi, 3)
                ACC1(ua.z, ub.z, c1.x, bflo, 4)
                ACC1(ua.z, ub.z, c1.y, bfhi, 5)
                ACC1(ua.w, ub.w, c1.z, bflo, 6)
                ACC1(ua.w, ub.w, c1.w, bfhi, 7)
                #undef ACC1
                if (jq < 8) outs += accv; else outc += accv;
            }
            svv = softplusf(outs + cst[WS_SC]);
            cvv = softplusf(outc + cst[WS_SC+1]);
        }
        u.svcv[ri] = packbf2(svv*gate, cvv*gate);
    }
    __syncthreads();

    // ---- stage 4: gated reduction + outputs + per-block partials ----
    if (tid < 64) {
        const int pos4 = tid >> 4, hh4 = (tid >> 2) & 3, qq = tid & 3;
        float svs = 0.f, cvs = 0.f, mass = 0.f;
        #pragma unroll
        for (int i = 0; i < 9; ++i) {
            int s = qq*9 + i;
            unsigned pp = u.svcv[pos4*144 + hh4*36 + s];
            svs += bflo(pp); cvs += bfhi(pp);
            int kk = s >> 2, h2 = s & 3;
            int nbr = ((pos4 >> 1) + kk/3)*4 + ((pos4 & 1) + kk%3);
            mass += sact[nbr*4 + h2];
        }
        svs += __shfl_xor(svs, 1); cvs += __shfl_xor(cvs, 1); mass += __shfl_xor(mass, 1);
        svs += __shfl_xor(svs, 2); cvs += __shfl_xor(cvs, 2); mass += __shfl_xor(mass, 2);
        float bl = 0.f, en = 0.f, ar = 0.f;
        if (qq == 0) {
            mass = fmaxf(mass, 1e-6f);
            const float support  = svs / mass;
            const float conflict = cvs / mass;
            const int bph = (b*PPOS + (y0 + (pos4 >> 1))*SIDE + x0 + (pos4 & 1))*NHYP + hh4;
            const float pd = drive[bph]  + support;
            const float pr = resist[bph] + conflict;
            float e = fminf(fmaxf(pd - pr + cst[WS_SC+2], -3.f), 3.f);
            const float a = 1.f / (1.f + expf(-e));
            out[0*NOUT + bph] = support;
            out[1*NOUT + bph] = conflict;
            out[2*NOUT + bph] = pd;
            out[3*NOUT + bph] = pr;
            out[4*NOUT + bph] = e;
            out[5*NOUT + bph] = a;
            out[6*NOUT + bph] = mass;
            bl = a;
            en = -(a*logf(a + 1e-8f) + (1.f - a)*logf(1.f - a + 1e-8f));
            ar = (a > 0.5f) ? 1.f : 0.f;
        }
        #pragma unroll
        for (int off = 32; off > 0; off >>= 1) {
            bl += __shfl_down(bl, off); en += __shfl_down(en, off); ar += __shfl_down(ar, off);
        }
        if (tid == 0) {
            part[blk]          = bl;
            part[NBLK + blk]   = en;
            part[2*NBLK + blk] = ar;
        }
    }
}

// ---------------- final: reduce per-block partials ----------------
__global__ __launch_bounds__(256) void eml_final(const float* __restrict__ part, float* __restrict__ out3)
{
    __shared__ float red[4*3];
    float bl = 0.f, en = 0.f, ar = 0.f;
    for (int i = threadIdx.x; i < NBLK; i += 256) {
        bl += part[i];
        en += part[NBLK + i];
        ar += part[2*NBLK + i];
    }
    #pragma unroll
    for (int off = 32; off > 0; off >>= 1) {
        bl += __shfl_down(bl, off); en += __shfl_down(en, off); ar += __shfl_down(ar, off);
    }
    const int lane = threadIdx.x & 63, wid = threadIdx.x >> 6;
    if (lane == 0) { red[wid*3] = bl; red[wid*3+1] = en; red[wid*3+2] = ar; }
    __syncthreads();
    if (threadIdx.x == 0) {
        float b2 = 0.f, e2 = 0.f, a2 = 0.f;
        for (int w = 0; w < 4; ++w) { b2 += red[w*3]; e2 += red[w*3+1]; a2 += red[w*3+2]; }
        const float inv = 1.0f / (float)NOUT;
        out3[0] = b2*inv; out3[1] = e2*inv; out3[2] = a2*inv;
    }
}

extern "C" void kernel_launch(void* const* d_in, const int* in_sizes, int n_in,
                              void* d_out, int out_size, void* d_ws, size_t ws_size,
                              hipStream_t stream)
{
    (void)in_sizes; (void)n_in; (void)out_size; (void)ws_size;
    const float* hs    = (const float*)d_in[0];
    const float* act   = (const float*)d_in[1];
    const float* drv   = (const float*)d_in[2];
    const float* res   = (const float*)d_in[3];
    const float* rel   = (const float*)d_in[4];
    const float* lnw   = (const float*)d_in[5];
    const float* lnb   = (const float*)d_in[6];
    const float* sw1   = (const float*)d_in[7];
    const float* sb1   = (const float*)d_in[8];
    const float* sw2   = (const float*)d_in[9];
    const float* sb2   = (const float*)d_in[10];
    const float* cw1   = (const float*)d_in[11];
    const float* cb1   = (const float*)d_in[12];
    const float* cw2   = (const float*)d_in[13];
    const float* cb2   = (const float*)d_in[14];
    const float* ebias = (const float*)d_in[15];
    float* out = (float*)d_out;
    float* ws  = (float*)d_ws;

    eml_fold<<<dim3(11), dim3(512), 0, stream>>>(
        rel, lnw, lnb, sw1, sb1, sw2, sb2, cw1, cb1, cw2, cb2, ebias, ws);
    eml_main<<<dim3(NBLK), dim3(THREADS), 0, stream>>>(
        hs, act, drv, res, out, ws, ws + WS_PART);
    eml_final<<<dim3(1), dim3(256), 0, stream>>>(ws + WS_PART, out + 7*NOUT);
}

// Round 14
// 48.849 us; speedup vs baseline: 1.0713x; 1.0713x over previous
//
#include <hip/hip_runtime.h>
#include <hip/hip_bf16.h>
#include <math.h>

#define SIDE 48
#define PPOS (SIDE*SIDE)
#define NBATCH 2
#define NHYP 4
#define FD 32
#define RD 8
#define NJ 104
#define NBP (NBATCH*PPOS)       // 4608
#define NOUT (NBP*NHYP)         // 18432
#define THREADS 512
#define NROWS 576
#define NBLK (NBP/4)            // 1152 (2x2 tiles: 24x24x2)
// d_ws dword offsets
#define WS_SR   16              // 9 f32
#define WS_SQR  28              // 9 f32
#define WS_SC   40              // 3 f32
#define WS_RC   64              // 9*128 f32
#define WS_S    1216            // 128 f32
#define WS_T    1344            // 128 f32 (pre-scaled: (T+b1)*32 + 512.5)
#define WS_W2   1472            // 128 f32
#define WS_WBF  1600            // 2048 dw
#define WS_WAF  3648            // 2048 dw
#define WS_PART 5696            // 3*NBLK f32
#define WS_TBL  9152            // 576 u32 row descriptors (sorted by srow)

typedef __attribute__((ext_vector_type(8))) short short8;
typedef __attribute__((ext_vector_type(4))) float f32x4;
typedef __attribute__((ext_vector_type(2))) float f32x2;
union U8 { uint4 u4; short8 s8; };

__device__ __forceinline__ float bflo(unsigned u) { return __uint_as_float(u << 16); }
__device__ __forceinline__ float bfhi(unsigned u) { return __uint_as_float(u & 0xffff0000u); }
__device__ __forceinline__ unsigned packbf2(float a, float b) {
    unsigned ua = __float_as_uint(a), ub = __float_as_uint(b);
    unsigned ra = (ua + 0x7fffu + ((ua >> 16) & 1u)) >> 16;
    unsigned rb = (ub + 0x7fffu + ((ub >> 16) & 1u)) & 0xffff0000u;
    return ra | rb;
}
__device__ __forceinline__ float softplusf(float v) {
    return fmaxf(v, 0.f) + log1pf(expf(-fabsf(v)));
}

#define W1X(kk, j) ((j) < 64 ? sup_w1[(kk)*64 + (j)] : con_w1[(kk)*64 + (j) - 64])

// ---------------- pre-kernel: fold weights once (11 blocks) ----------------
__global__ __launch_bounds__(512) void eml_fold(
    const float* __restrict__ rel, const float* __restrict__ ln_w, const float* __restrict__ ln_b,
    const float* __restrict__ sup_w1, const float* __restrict__ sup_b1,
    const float* __restrict__ sup_w2, const float* __restrict__ sup_b2,
    const float* __restrict__ con_w1, const float* __restrict__ con_b1,
    const float* __restrict__ con_w2, const float* __restrict__ con_b2,
    const float* __restrict__ eml_bias, float* __restrict__ ws)
{
    const int tid = threadIdx.x;
    const int bid = blockIdx.x;
    unsigned* wsd = reinterpret_cast<unsigned*>(ws);
    __shared__ float pS[4][128], pT[4][128];

    if (bid < 8) {
        // B-fragments: lane l holds W^T[col][k] pairs, k0=(l>>4)*8+2j
        int u = bid*512 + tid;
        int sel = u >> 11, v2 = u & 2047;
        int n = v2 >> 8, l = (v2 >> 2) & 63, j = v2 & 3;
        int k0 = (l >> 4)*8 + 2*j, col = n*16 + (l & 15);
        float lo, hi;
        if (sel == 0) {   // Wb (src)
            lo = ln_w[32+k0]*W1X(32+k0,col)     - ln_w[64+k0]*W1X(64+k0,col);
            hi = ln_w[32+k0+1]*W1X(32+k0+1,col) - ln_w[64+k0+1]*W1X(64+k0+1,col);
        } else {          // Wa (tgt)
            lo = ln_w[k0]*W1X(k0,col)     + ln_w[64+k0]*W1X(64+k0,col);
            hi = ln_w[k0+1]*W1X(k0+1,col) + ln_w[64+k0+1]*W1X(64+k0+1,col);
        }
        wsd[(sel ? WS_WAF : WS_WBF) + v2] = packbf2(lo, hi);
    } else if (bid == 8) {
        #pragma unroll
        for (int u0 = 0; u0 < 2; ++u0) {
            int u = u0*512 + tid;               // rc entries 0..1023
            int k = u >> 7, j = u & 127;
            float a = 0.f;
            #pragma unroll
            for (int i = 0; i < 8; ++i) a += rel[k*8+i] * ln_w[96+i] * W1X(96+i, j);
            ws[WS_RC + u] = a;
        }
    } else if (bid == 9) {
        if (tid < 128) {
            int u = 1024 + tid;                 // rc entries 1024..1151
            int k = u >> 7, j = u & 127;
            float a = 0.f;
            #pragma unroll
            for (int i = 0; i < 8; ++i) a += rel[k*8+i] * ln_w[96+i] * W1X(96+i, j);
            ws[WS_RC + u] = a;
        } else if (tid < 137) {
            int kk = tid - 128;
            float s = 0.f, sq = 0.f;
            #pragma unroll
            for (int i = 0; i < 8; ++i) { float v = rel[kk*8+i]; s += v; sq += v*v; }
            ws[WS_SR+kk] = s; ws[WS_SQR+kk] = sq;
        } else if (tid == 140) {
            ws[WS_SC] = sup_b2[0]; ws[WS_SC+1] = con_b2[0]; ws[WS_SC+2] = eml_bias[0];
        } else if (tid >= 256) {
            // build srow-sorted row-descriptor table (one (srow,pos) unit per thread)
            int t = tid - 256;                  // 0..255
            int srow = t >> 2, pos = t & 3;
            int nbr = srow >> 2;
            int h2  = srow & 3;
            int ny = nbr >> 2, nx = nbr & 3;
            int py = pos >> 1, px = pos & 1;
            int ky = ny - py, kx = nx - px;
            bool val = (ky >= 0) && (ky < 3) && (kx >= 0) && (kx < 3);
            const int c0 = 1, c1 = 2, c2 = 2, c3 = 1;
            int cy[4] = {c0, c1, c2, c3};
            int P = 0;
            for (int n = 0; n < nbr; ++n) P += cy[n >> 2] * cy[n & 3];
            int npos = cy[ny] * cy[nx];
            int pr = 0;
            for (int p2 = 0; p2 < pos; ++p2) {
                int ky2 = ny - (p2 >> 1), kx2 = nx - (p2 & 1);
                if (ky2 >= 0 && ky2 < 3 && kx2 >= 0 && kx2 < 3) ++pr;
            }
            if (val) {
                int k = ky*3 + kx;
                int off = 16*P + h2*4*npos + pr*4;
                unsigned base = (unsigned)(srow | (pos << 6) | (k << 10));
                #pragma unroll
                for (int hh = 0; hh < 4; ++hh)
                    wsd[WS_TBL + off + hh] = base | (unsigned)(hh << 8);
            }
        }
    } else {
        // S/T/W2: 4-way split over k
        int col = tid & 127, seg = tid >> 7;
        float S = 0.f, T = 0.f;
        for (int kk = seg*26; kk < seg*26 + 26; ++kk) {
            float w = W1X(kk, col);
            S += ln_w[kk]*w; T += ln_b[kk]*w;
        }
        pS[seg][col] = S; pT[seg][col] = T;
        __syncthreads();
        if (tid < 128) {
            float Tt = pT[0][tid] + pT[1][tid] + pT[2][tid] + pT[3][tid]
                       + (tid < 64 ? sup_b1[tid] : con_b1[tid-64]);
            ws[WS_S + tid]  = pS[0][tid] + pS[1][tid] + pS[2][tid] + pS[3][tid];
            ws[WS_T + tid]  = Tt * 32.f + 512.5f;     // pre-scaled for LUT quantize
            ws[WS_W2 + tid] = (tid < 64 ? sup_w2[tid] : con_w2[tid-64]);
        }
    }
}

// ---------------- main kernel: one 2x2 position tile per block ----------------
__global__ __launch_bounds__(THREADS, 8) void eml_main(
    const float* __restrict__ hs, const float* __restrict__ act_in,
    const float* __restrict__ drive, const float* __restrict__ resist,
    float* __restrict__ out, const float* __restrict__ cst,
    float* __restrict__ part)
{
    __shared__ __align__(16) unsigned sB[64*68];    // 17408 B src@Wb bf16-pair
    __shared__ __align__(16) float    sA[16*132];   // 8448 B  tgt@Wa f32
    __shared__ union __align__(16) UU {
        __hip_bfloat16 snb[64*40];                  // 5120 B (dead after stage 2)
        unsigned svcv[NROWS];                       // 2304 B (stage 3-4)
    } u;
    __shared__ __align__(16) float sdot[64*16];     // 4096 B [srow][cidx]
    __shared__ __align__(16) float sgelu[1024];     // 4096 B exact-GELU LUT, h=1/32
    __shared__ float sact[64], sSt[64], sSq[64];    // 768 B
    __shared__ float sSr[9], sSqr[9];               // 72 B

    const int tid = threadIdx.x;
    const int blk = blockIdx.x;
    const int b   = blk / 576;
    const int rm  = blk % 576;
    const int y0  = (rm / 24) * 2;
    const int x0  = (rm % 24) * 2;

    // ---- stage 0: GELU LUT ----
    #pragma unroll
    for (int i = tid; i < 1024; i += THREADS) {
        float x = (float)(i - 512) * 0.03125f;
        sgelu[i] = 0.5f * x * (1.0f + erff(x * 0.70710678118654752f));
    }

    // ---- stage 1: 64 halo vectors (4x4 positions x 4 hyp) ----
    const int vec = tid >> 3, q = tid & 7;       // 64 vecs x 8 threads
    const int nb1 = vec >> 2, h1 = vec & 3;
    const int yy = y0 + (nb1 >> 2) - 1, xx = x0 + (nb1 & 3) - 1;
    const bool vld = (yy >= 0) && (yy < SIDE) && (xx >= 0) && (xx < SIDE);
    const int npos = b*PPOS + yy*SIDE + xx;
    float4 v = make_float4(0.f, 0.f, 0.f, 0.f);
    if (vld) v = *reinterpret_cast<const float4*>(&hs[((size_t)npos*NHYP + h1)*FD + q*4]);
    {
        unsigned* drow = reinterpret_cast<unsigned*>(&u.snb[vec*40]);
        drow[q*2]   = packbf2(v.x, v.y);
        drow[q*2+1] = packbf2(v.z, v.w);
        float s  = v.x + v.y + v.z + v.w;
        float sq = v.x*v.x + v.y*v.y + v.z*v.z + v.w*v.w;
        s += __shfl_xor(s, 1); sq += __shfl_xor(sq, 1);
        s += __shfl_xor(s, 2); sq += __shfl_xor(sq, 2);
        s += __shfl_xor(s, 4); sq += __shfl_xor(sq, 4);
        if (q == 0) {
            sSt[vec] = s; sSq[vec] = sq;
            sact[vec] = vld ? act_in[npos*NHYP + h1] : 0.f;
        }
    }
    if (tid < 9) { sSr[tid] = cst[WS_SR+tid]; sSqr[tid] = cst[WS_SQR+tid]; }
    __syncthreads();

    // ---- stage 2: MFMA GEMMs (8 waves; G3 on waves 0-3) ----
    {
        const int wv = tid >> 6, lane = tid & 63;
        const int fr = lane & 15, fq = lane >> 4;
        const char* snbB = reinterpret_cast<const char*>(u.snb);
        U8 bB, bA;
        bB.u4 = reinterpret_cast<const uint4*>(cst + WS_WBF)[wv*64 + lane];
        bA.u4 = reinterpret_cast<const uint4*>(cst + WS_WAF)[wv*64 + lane];
        // G1: src (64 rows) @ Wb -> sB bf16-pair
        #pragma unroll
        for (int m = 0; m < 4; ++m) {
            U8 a; a.u4 = *reinterpret_cast<const uint4*>(snbB + (m*16 + fr)*80 + fq*16);
            f32x4 acc = {0.f, 0.f, 0.f, 0.f};
            acc = __builtin_amdgcn_mfma_f32_16x16x32_bf16(a.s8, bB.s8, acc, 0, 0, 0);
            #pragma unroll
            for (int j = 0; j < 4; ++j) {
                float o = __shfl_xor(acc[j], 1);
                if (!(lane & 1))
                    sB[(m*16 + fq*4 + j)*68 + wv*8 + (fr >> 1)] = packbf2(acc[j], o);
            }
        }
        // G2: tgt (16 center rows: snb 20-27, 36-43) @ Wa -> sA f32
        const int trow = (fr < 8) ? (20 + fr) : (28 + fr);
        U8 at; at.u4 = *reinterpret_cast<const uint4*>(snbB + trow*80 + fq*16);
        {
            f32x4 acc = {0.f, 0.f, 0.f, 0.f};
            acc = __builtin_amdgcn_mfma_f32_16x16x32_bf16(at.s8, bA.s8, acc, 0, 0, 0);
            #pragma unroll
            for (int j = 0; j < 4; ++j)
                sA[(fq*4 + j)*132 + wv*16 + fr] = acc[j];
        }
        // G3: dot[srow][cidx] = tgt @ src^T (waves 0-3, n-tile = wv)
        if (wv < 4) {
            U8 s2; s2.u4 = *reinterpret_cast<const uint4*>(snbB + (wv*16 + fr)*80 + fq*16);
            f32x4 acc = {0.f, 0.f, 0.f, 0.f};
            acc = __builtin_amdgcn_mfma_f32_16x16x32_bf16(at.s8, s2.s8, acc, 0, 0, 0);
            *reinterpret_cast<f32x4*>(&sdot[(wv*16 + fr)*16 + fq*4]) = acc;
        }
    }
    __syncthreads();

    // ---- stage 3: per-row epilogue, rows sorted by srow (conflict-free sB) ----
    for (int ri = tid; ri < NROWS; ri += THREADS) {
        const unsigned desc = reinterpret_cast<const unsigned*>(cst)[WS_TBL + ri];
        const int srow = desc & 63;
        const int pos  = (desc >> 6) & 3;
        const int hh   = (desc >> 8) & 3;
        const int k    = desc >> 10;
        const int h2   = srow & 3;
        const float gate = sact[srow];
        float svv = 0.f, cvv = 0.f;
        if (gate > 0.f) {
            const int cidx = pos*4 + hh;
            const int crow = (pos < 2 ? 20 : 28) + cidx;
            const float dot = sdot[srow*16 + cidx];
            const float mu   = (2.f*sSt[crow] + sSr[k]) * (1.f/NJ);
            const float ssum = 2.f*sSq[crow] + 2.f*sSq[srow] - 2.f*dot + sSqr[k];
            const float rinv = rsqrtf(ssum*(1.f/NJ) - mu*mu + 1e-5f);
            const float r32  = rinv * 32.f;
            const float b32  = -mu * r32;
            const f32x2 r32_2 = {r32, r32};
            const f32x2 b32_2 = {b32, b32};
            const float* aR  = &sA[cidx*132];
            const uint4* bR  = reinterpret_cast<const uint4*>(&sB[srow*68]);
            const float* rck = cst + WS_RC + k*128;
            const f32x2* S2  = reinterpret_cast<const f32x2*>(cst + WS_S);
            const f32x2* T2  = reinterpret_cast<const f32x2*>(cst + WS_T);
            float outs = 0.f, outc = 0.f;
            #pragma unroll 2
            for (int jq = 0; jq < 16; ++jq) {
                uint4 ub = bR[jq];
                const f32x2* a2 = reinterpret_cast<const f32x2*>(aR + jq*8);
                const f32x2* c2 = reinterpret_cast<const f32x2*>(rck + jq*8);
                float accv = 0.f;
                #define PAIR(UW, P) { \
                    f32x2 bv; bv.x = bflo(UW); bv.y = bfhi(UW); \
                    f32x2 d  = a2[P] + bv + c2[P]; \
                    f32x2 qv = r32_2*d + (b32_2*S2[jq*4+P] + T2[jq*4+P]); \
                    float g0 = sgelu[(unsigned)qv.x]; \
                    float g1 = sgelu[(unsigned)qv.y]; \
                    accv = fmaf(g0, cst[WS_W2 + jq*8 + 2*(P)], accv); \
                    accv = fmaf(g1, cst[WS_W2 + jq*8 + 2*(P) + 1], accv); }
                PAIR(ub.x, 0)
                PAIR(ub.y, 1)
                PAIR(ub.z, 2)
                PAIR(ub.w, 3)
                #undef PAIR
                if (jq < 8) outs += accv; else outc += accv;
            }
            svv = softplusf(outs + cst[WS_SC]);
            cvv = softplusf(outc + cst[WS_SC+1]);
        }
        const int orig = pos*144 + hh*36 + k*4 + h2;
        u.svcv[orig] = packbf2(svv*gate, cvv*gate);
    }
    __syncthreads();

    // ---- stage 4: gated reduction + outputs + per-block partials ----
    if (tid < 64) {
        const int pos4 = tid >> 4, hh4 = (tid >> 2) & 3, qq = tid & 3;
        float svs = 0.f, cvs = 0.f, mass = 0.f;
        #pragma unroll
        for (int i = 0; i < 9; ++i) {
            int s = qq*9 + i;
            unsigned pp = u.svcv[pos4*144 + hh4*36 + s];
            svs += bflo(pp); cvs += bfhi(pp);
            int kk = s >> 2, h2 = s & 3;
            int nbr = ((pos4 >> 1) + kk/3)*4 + ((pos4 & 1) + kk%3);
            mass += sact[nbr*4 + h2];
        }
        svs += __shfl_xor(svs, 1); cvs += __shfl_xor(cvs, 1); mass += __shfl_xor(mass, 1);
        svs += __shfl_xor(svs, 2); cvs += __shfl_xor(cvs, 2); mass += __shfl_xor(mass, 2);
        float bl = 0.f, en = 0.f, ar = 0.f;
        if (qq == 0) {
            mass = fmaxf(mass, 1e-6f);
            const float support  = svs / mass;
            const float conflict = cvs / mass;
            const int bph = (b*PPOS + (y0 + (pos4 >> 1))*SIDE + x0 + (pos4 & 1))*NHYP + hh4;
            const float pd = drive[bph]  + support;
            const float pr = resist[bph] + conflict;
            float e = fminf(fmaxf(pd - pr + cst[WS_SC+2], -3.f), 3.f);
            const float a = 1.f / (1.f + expf(-e));
            out[0*NOUT + bph] = support;
            out[1*NOUT + bph] = conflict;
            out[2*NOUT + bph] = pd;
            out[3*NOUT + bph] = pr;
            out[4*NOUT + bph] = e;
            out[5*NOUT + bph] = a;
            out[6*NOUT + bph] = mass;
            bl = a;
            en = -(a*logf(a + 1e-8f) + (1.f - a)*logf(1.f - a + 1e-8f));
            ar = (a > 0.5f) ? 1.f : 0.f;
        }
        #pragma unroll
        for (int off = 32; off > 0; off >>= 1) {
            bl += __shfl_down(bl, off); en += __shfl_down(en, off); ar += __shfl_down(ar, off);
        }
        if (tid == 0) {
            part[blk]          = bl;
            part[NBLK + blk]   = en;
            part[2*NBLK + blk] = ar;
        }
    }
}

// ---------------- final: reduce per-block partials ----------------
__global__ __launch_bounds__(256) void eml_final(const float* __restrict__ part, float* __restrict__ out3)
{
    __shared__ float red[4*3];
    float bl = 0.f, en = 0.f, ar = 0.f;
    for (int i = threadIdx.x; i < NBLK; i += 256) {
        bl += part[i];
        en += part[NBLK + i];
        ar += part[2*NBLK + i];
    }
    #pragma unroll
    for (int off = 32; off > 0; off >>= 1) {
        bl += __shfl_down(bl, off); en += __shfl_down(en, off); ar += __shfl_down(ar, off);
    }
    const int lane = threadIdx.x & 63, wid = threadIdx.x >> 6;
    if (lane == 0) { red[wid*3] = bl; red[wid*3+1] = en; red[wid*3+2] = ar; }
    __syncthreads();
    if (threadIdx.x == 0) {
        float b2 = 0.f, e2 = 0.f, a2 = 0.f;
        for (int w = 0; w < 4; ++w) { b2 += red[w*3]; e2 += red[w*3+1]; a2 += red[w*3+2]; }
        const float inv = 1.0f / (float)NOUT;
        out3[0] = b2*inv; out3[1] = e2*inv; out3[2] = a2*inv;
    }
}

extern "C" void kernel_launch(void* const* d_in, const int* in_sizes, int n_in,
                              void* d_out, int out_size, void* d_ws, size_t ws_size,
                              hipStream_t stream)
{
    (void)in_sizes; (void)n_in; (void)out_size; (void)ws_size;
    const float* hs    = (const float*)d_in[0];
    const float* act   = (const float*)d_in[1];
    const float* drv   = (const float*)d_in[2];
    const float* res   = (const float*)d_in[3];
    const float* rel   = (const float*)d_in[4];
    const float* lnw   = (const float*)d_in[5];
    const float* lnb   = (const float*)d_in[6];
    const float* sw1   = (const float*)d_in[7];
    const float* sb1   = (const float*)d_in[8];
    const float* sw2   = (const float*)d_in[9];
    const float* sb2   = (const float*)d_in[10];
    const float* cw1   = (const float*)d_in[11];
    const float* cb1   = (const float*)d_in[12];
    const float* cw2   = (const float*)d_in[13];
    const float* cb2   = (const float*)d_in[14];
    const float* ebias = (const float*)d_in[15];
    float* out = (float*)d_out;
    float* ws  = (float*)d_ws;

    eml_fold<<<dim3(11), dim3(512), 0, stream>>>(
        rel, lnw, lnb, sw1, sb1, sw2, sb2, cw1, cb1, cw2, cb2, ebias, ws);
    eml_main<<<dim3(NBLK), dim3(THREADS), 0, stream>>>(
        hs, act, drv, res, out, ws, ws + WS_PART);
    eml_final<<<dim3(1), dim3(256), 0, stream>>>(ws + WS_PART, out + 7*NOUT);
}

// Round 15
// 44.592 us; speedup vs baseline: 1.1736x; 1.0955x over previous
//
#include <hip/hip_runtime.h>
#include <hip/hip_bf16.h>
#include <math.h>

#define SIDE 48
#define PPOS (SIDE*SIDE)
#define NBATCH 2
#define NHYP 4
#define FD 32
#define RD 8
#define NJ 104
#define NBP (NBATCH*PPOS)       // 4608
#define NOUT (NBP*NHYP)         // 18432
#define THREADS 512
#define NROWS 864               // 6 positions x 144 rows
#define NBLK 768                // 2 batches x (48/3) x (48/2) tiles, 3x2 positions
// d_ws dword offsets
#define WS_SR   16              // 9 f32
#define WS_SQR  28              // 9 f32
#define WS_SC   40              // 3 f32
#define WS_RC   64              // 9*128 f32
#define WS_S    1216            // 128 f32
#define WS_T    1344            // 128 f32 (pre-scaled: (T+b1)*32 + 512.5)
#define WS_W2   1472            // 128 f32
#define WS_WBF  1600            // 2048 dw
#define WS_WAF  3648            // 2048 dw
#define WS_PART 5696            // 3*NBLK f32

typedef __attribute__((ext_vector_type(8))) short short8;
typedef __attribute__((ext_vector_type(4))) float f32x4;
typedef __attribute__((ext_vector_type(2))) float f32x2;
union U8 { uint4 u4; short8 s8; };

__device__ __forceinline__ float bflo(unsigned u) { return __uint_as_float(u << 16); }
__device__ __forceinline__ float bfhi(unsigned u) { return __uint_as_float(u & 0xffff0000u); }
__device__ __forceinline__ unsigned packbf2(float a, float b) {
    unsigned ua = __float_as_uint(a), ub = __float_as_uint(b);
    unsigned ra = (ua + 0x7fffu + ((ua >> 16) & 1u)) >> 16;
    unsigned rb = (ub + 0x7fffu + ((ub >> 16) & 1u)) & 0xffff0000u;
    return ra | rb;
}
__device__ __forceinline__ float softplusf(float v) {
    return fmaxf(v, 0.f) + log1pf(expf(-fabsf(v)));
}

#define W1X(kk, j) ((j) < 64 ? sup_w1[(kk)*64 + (j)] : con_w1[(kk)*64 + (j) - 64])

// ---------------- pre-kernel: fold weights once (11 blocks) ----------------
__global__ __launch_bounds__(512) void eml_fold(
    const float* __restrict__ rel, const float* __restrict__ ln_w, const float* __restrict__ ln_b,
    const float* __restrict__ sup_w1, const float* __restrict__ sup_b1,
    const float* __restrict__ sup_w2, const float* __restrict__ sup_b2,
    const float* __restrict__ con_w1, const float* __restrict__ con_b1,
    const float* __restrict__ con_w2, const float* __restrict__ con_b2,
    const float* __restrict__ eml_bias, float* __restrict__ ws)
{
    const int tid = threadIdx.x;
    const int bid = blockIdx.x;
    unsigned* wsd = reinterpret_cast<unsigned*>(ws);
    __shared__ float pS[4][128], pT[4][128];

    if (bid < 8) {
        // B-fragments: lane l holds W^T[col][k] pairs, k0=(l>>4)*8+2j
        int u = bid*512 + tid;
        int sel = u >> 11, v2 = u & 2047;
        int n = v2 >> 8, l = (v2 >> 2) & 63, j = v2 & 3;
        int k0 = (l >> 4)*8 + 2*j, col = n*16 + (l & 15);
        float lo, hi;
        if (sel == 0) {   // Wb (src)
            lo = ln_w[32+k0]*W1X(32+k0,col)     - ln_w[64+k0]*W1X(64+k0,col);
            hi = ln_w[32+k0+1]*W1X(32+k0+1,col) - ln_w[64+k0+1]*W1X(64+k0+1,col);
        } else {          // Wa (tgt)
            lo = ln_w[k0]*W1X(k0,col)     + ln_w[64+k0]*W1X(64+k0,col);
            hi = ln_w[k0+1]*W1X(k0+1,col) + ln_w[64+k0+1]*W1X(64+k0+1,col);
        }
        wsd[(sel ? WS_WAF : WS_WBF) + v2] = packbf2(lo, hi);
    } else if (bid == 8) {
        #pragma unroll
        for (int u0 = 0; u0 < 2; ++u0) {
            int u = u0*512 + tid;               // rc entries 0..1023
            int k = u >> 7, j = u & 127;
            float a = 0.f;
            #pragma unroll
            for (int i = 0; i < 8; ++i) a += rel[k*8+i] * ln_w[96+i] * W1X(96+i, j);
            ws[WS_RC + u] = a;
        }
    } else if (bid == 9) {
        if (tid < 128) {
            int u = 1024 + tid;                 // rc entries 1024..1151
            int k = u >> 7, j = u & 127;
            float a = 0.f;
            #pragma unroll
            for (int i = 0; i < 8; ++i) a += rel[k*8+i] * ln_w[96+i] * W1X(96+i, j);
            ws[WS_RC + u] = a;
        } else if (tid < 137) {
            int kk = tid - 128;
            float s = 0.f, sq = 0.f;
            #pragma unroll
            for (int i = 0; i < 8; ++i) { float v = rel[kk*8+i]; s += v; sq += v*v; }
            ws[WS_SR+kk] = s; ws[WS_SQR+kk] = sq;
        } else if (tid == 140) {
            ws[WS_SC] = sup_b2[0]; ws[WS_SC+1] = con_b2[0]; ws[WS_SC+2] = eml_bias[0];
        }
    } else {
        // S/T/W2: 4-way split over k
        int col = tid & 127, seg = tid >> 7;
        float S = 0.f, T = 0.f;
        for (int kk = seg*26; kk < seg*26 + 26; ++kk) {
            float w = W1X(kk, col);
            S += ln_w[kk]*w; T += ln_b[kk]*w;
        }
        pS[seg][col] = S; pT[seg][col] = T;
        __syncthreads();
        if (tid < 128) {
            float Tt = pT[0][tid] + pT[1][tid] + pT[2][tid] + pT[3][tid]
                       + (tid < 64 ? sup_b1[tid] : con_b1[tid-64]);
            ws[WS_S + tid]  = pS[0][tid] + pS[1][tid] + pS[2][tid] + pS[3][tid];
            ws[WS_T + tid]  = Tt * 32.f + 512.5f;     // pre-scaled for LUT quantize
            ws[WS_W2 + tid] = (tid < 64 ? sup_w2[tid] : con_w2[tid-64]);
        }
    }
}

// ---------------- main kernel: one 3x2 position tile per block (one-round grid) ----------------
__global__ __launch_bounds__(THREADS, 6) void eml_main(
    const float* __restrict__ hs, const float* __restrict__ act_in,
    const float* __restrict__ drive, const float* __restrict__ resist,
    float* __restrict__ out, const float* __restrict__ cst,
    float* __restrict__ part)
{
    __shared__ __align__(16) unsigned sB[80*68];    // 21760 B src@Wb bf16-pair
    __shared__ __align__(16) float    sA[24*132];   // 12672 B tgt@Wa f32
    __shared__ union __align__(16) UU {
        __hip_bfloat16 snb[80*40];                  // 6400 B (dead after stage 2)
        unsigned svcv[NROWS];                       // 3456 B (stage 3-4)
    } u;
    __shared__ __align__(16) float sdot[80*24];     // 7680 B [srow][ctr]
    __shared__ __align__(16) float sgelu[1024];     // 4096 B exact-GELU LUT, h=1/32
    __shared__ float sact[80], sSt[80], sSq[80];    // 960 B
    __shared__ float sSr[9], sSqr[9];               // 72 B

    const int tid = threadIdx.x;
    const int blk = blockIdx.x;
    const int b   = blk / 384;
    const int rm  = blk % 384;
    const int y0  = (rm / 16) * 2;   // 24 tiles along y
    const int x0  = (rm % 16) * 3;   // 16 tiles along x

    // ---- stage 0: GELU LUT ----
    #pragma unroll
    for (int i = tid; i < 1024; i += THREADS) {
        float x = (float)(i - 512) * 0.03125f;
        sgelu[i] = 0.5f * x * (1.0f + erff(x * 0.70710678118654752f));
    }

    // ---- stage 1: 80 halo vectors (4y x 5x positions x 4 hyp), 4 threads/vec ----
    if (tid < 320) {
        const int vec = tid >> 2, q = tid & 3;
        const int nb1 = vec >> 2, h1 = vec & 3;
        const int ny = nb1 / 5, nx = nb1 % 5;
        const int yy = y0 + ny - 1, xx = x0 + nx - 1;
        const bool vld = (yy >= 0) && (yy < SIDE) && (xx >= 0) && (xx < SIDE);
        const int npos = b*PPOS + yy*SIDE + xx;
        float4 v0 = make_float4(0.f,0.f,0.f,0.f), v1 = make_float4(0.f,0.f,0.f,0.f);
        if (vld) {
            const float4* p = reinterpret_cast<const float4*>(&hs[((size_t)npos*NHYP + h1)*FD + q*8]);
            v0 = p[0]; v1 = p[1];
        }
        unsigned* drow = reinterpret_cast<unsigned*>(&u.snb[vec*40]);
        drow[q*4+0] = packbf2(v0.x, v0.y);
        drow[q*4+1] = packbf2(v0.z, v0.w);
        drow[q*4+2] = packbf2(v1.x, v1.y);
        drow[q*4+3] = packbf2(v1.z, v1.w);
        float s  = (v0.x+v0.y+v0.z+v0.w) + (v1.x+v1.y+v1.z+v1.w);
        float sq = (v0.x*v0.x+v0.y*v0.y+v0.z*v0.z+v0.w*v0.w)
                 + (v1.x*v1.x+v1.y*v1.y+v1.z*v1.z+v1.w*v1.w);
        s += __shfl_xor(s, 1); sq += __shfl_xor(sq, 1);
        s += __shfl_xor(s, 2); sq += __shfl_xor(sq, 2);
        if (q == 0) {
            sSt[vec] = s; sSq[vec] = sq;
            sact[vec] = vld ? act_in[npos*NHYP + h1] : 0.f;
        }
    }
    if (tid < 9) { sSr[tid] = cst[WS_SR+tid]; sSqr[tid] = cst[WS_SQR+tid]; }
    __syncthreads();

    // ---- stage 2: MFMA GEMMs (8 waves) ----
    {
        const int wv = tid >> 6, lane = tid & 63;
        const int fr = lane & 15, fq = lane >> 4;
        const char* snbB = reinterpret_cast<const char*>(u.snb);
        U8 bB, bA;
        bB.u4 = reinterpret_cast<const uint4*>(cst + WS_WBF)[wv*64 + lane];
        bA.u4 = reinterpret_cast<const uint4*>(cst + WS_WAF)[wv*64 + lane];
        // G1: src (80 rows, 5 m-tiles) @ Wb -> sB bf16-pair
        #pragma unroll
        for (int m = 0; m < 5; ++m) {
            U8 a; a.u4 = *reinterpret_cast<const uint4*>(snbB + (m*16 + fr)*80 + fq*16);
            f32x4 acc = {0.f, 0.f, 0.f, 0.f};
            acc = __builtin_amdgcn_mfma_f32_16x16x32_bf16(a.s8, bB.s8, acc, 0, 0, 0);
            #pragma unroll
            for (int j = 0; j < 4; ++j) {
                float o = __shfl_xor(acc[j], 1);
                if (!(lane & 1))
                    sB[(m*16 + fq*4 + j)*68 + wv*8 + (fr >> 1)] = packbf2(acc[j], o);
            }
        }
        // tgt fragments: ctr t = pos*4+hh, pos = py*3+px; snb row = ((py+1)*5 + px+1)*4 + hh
        const int pos0 = fr >> 2, hh0 = fr & 3;
        const int trow0 = ((pos0/3 + 1)*5 + (pos0%3) + 1)*4 + hh0;
        int trow1 = 0;
        if (fr < 8) {
            const int t1 = 16 + fr, pos1 = t1 >> 2, hh1 = t1 & 3;
            trow1 = ((pos1/3 + 1)*5 + (pos1%3) + 1)*4 + hh1;
        }
        U8 at0, at1;
        at0.u4 = *reinterpret_cast<const uint4*>(snbB + trow0*80 + fq*16);
        at1.u4 = *reinterpret_cast<const uint4*>(snbB + trow1*80 + fq*16);
        // G2: tgt @ Wa -> sA f32 (24 rows)
        {
            f32x4 acc = {0.f, 0.f, 0.f, 0.f};
            acc = __builtin_amdgcn_mfma_f32_16x16x32_bf16(at0.s8, bA.s8, acc, 0, 0, 0);
            #pragma unroll
            for (int j = 0; j < 4; ++j)
                sA[(fq*4 + j)*132 + wv*16 + fr] = acc[j];
        }
        {
            f32x4 acc = {0.f, 0.f, 0.f, 0.f};
            acc = __builtin_amdgcn_mfma_f32_16x16x32_bf16(at1.s8, bA.s8, acc, 0, 0, 0);
            if (fq < 2) {
                #pragma unroll
                for (int j = 0; j < 4; ++j)
                    sA[(16 + fq*4 + j)*132 + wv*16 + fr] = acc[j];
            }
        }
        // G3: dot[src][ctr] = tgt @ src^T : 10 units (2 mt x 5 n) over 8 waves
        #pragma unroll
        for (int pass = 0; pass < 2; ++pass) {
            int uu = pass ? (8 + wv) : wv;
            if (pass && wv >= 2) break;
            const int mt = uu / 5, n = uu % 5;
            U8 sfr; sfr.u4 = *reinterpret_cast<const uint4*>(snbB + (n*16 + fr)*80 + fq*16);
            f32x4 acc = {0.f, 0.f, 0.f, 0.f};
            acc = __builtin_amdgcn_mfma_f32_16x16x32_bf16(mt ? at1.s8 : at0.s8, sfr.s8, acc, 0, 0, 0);
            if (!mt)
                *reinterpret_cast<f32x4*>(&sdot[(n*16 + fr)*24 + fq*4]) = acc;
            else if (fq < 2)
                *reinterpret_cast<f32x4*>(&sdot[(n*16 + fr)*24 + 16 + fq*4]) = acc;
        }
    }
    __syncthreads();

    // ---- stage 3: per-row epilogue (864 rows; f32x2 pairs; LUT; no clamp) ----
    for (int ri = tid; ri < NROWS; ri += THREADS) {
        const int pos = ri / 144, r = ri % 144;
        const int hh = r / 36, s = r % 36, k = s >> 2, h2 = s & 3;
        const int py = pos / 3, px = pos % 3;
        const int nbr  = (py + k/3)*5 + (px + k%3);
        const int srow = nbr*4 + h2;
        const float gate = sact[srow];
        float svv = 0.f, cvv = 0.f;
        if (gate > 0.f) {
            const int cidx = pos*4 + hh;
            const int crow = ((py + 1)*5 + px + 1)*4 + hh;
            const float dot = sdot[srow*24 + cidx];
            const float mu   = (2.f*sSt[crow] + sSr[k]) * (1.f/NJ);
            const float ssum = 2.f*sSq[crow] + 2.f*sSq[srow] - 2.f*dot + sSqr[k];
            const float rinv = rsqrtf(ssum*(1.f/NJ) - mu*mu + 1e-5f);
            const float r32  = rinv * 32.f;
            const float b32  = -mu * r32;
            const f32x2 r32_2 = {r32, r32};
            const f32x2 b32_2 = {b32, b32};
            const float* aR  = &sA[cidx*132];
            const uint4* bR  = reinterpret_cast<const uint4*>(&sB[srow*68]);
            const float* rck = cst + WS_RC + k*128;
            const f32x2* S2  = reinterpret_cast<const f32x2*>(cst + WS_S);
            const f32x2* T2  = reinterpret_cast<const f32x2*>(cst + WS_T);
            float outs = 0.f, outc = 0.f;
            #pragma unroll 2
            for (int jq = 0; jq < 16; ++jq) {
                uint4 ub = bR[jq];
                const f32x2* a2 = reinterpret_cast<const f32x2*>(aR + jq*8);
                const f32x2* c2 = reinterpret_cast<const f32x2*>(rck + jq*8);
                float accv = 0.f;
                #define PAIR(UW, P) { \
                    f32x2 bv; bv.x = bflo(UW); bv.y = bfhi(UW); \
                    f32x2 d  = a2[P] + bv + c2[P]; \
                    f32x2 qv = r32_2*d + (b32_2*S2[jq*4+P] + T2[jq*4+P]); \
                    float g0 = sgelu[(unsigned)qv.x]; \
                    float g1 = sgelu[(unsigned)qv.y]; \
                    accv = fmaf(g0, cst[WS_W2 + jq*8 + 2*(P)], accv); \
                    accv = fmaf(g1, cst[WS_W2 + jq*8 + 2*(P) + 1], accv); }
                PAIR(ub.x, 0)
                PAIR(ub.y, 1)
                PAIR(ub.z, 2)
                PAIR(ub.w, 3)
                #undef PAIR
                if (jq < 8) outs += accv; else outc += accv;
            }
            svv = softplusf(outs + cst[WS_SC]);
            cvv = softplusf(outc + cst[WS_SC+1]);
        }
        u.svcv[ri] = packbf2(svv*gate, cvv*gate);
    }
    __syncthreads();

    // ---- stage 4: gated reduction + outputs + per-block partials ----
    float bl = 0.f, en = 0.f, ar = 0.f;
    if (tid < 96) {
        const int g = tid >> 2, qq = tid & 3;    // g = pos*4+hh
        const int pos4 = g >> 2, hh4 = g & 3;
        const int py = pos4 / 3, px = pos4 % 3;
        float svs = 0.f, cvs = 0.f, mass = 0.f;
        #pragma unroll
        for (int i = 0; i < 9; ++i) {
            int s = qq*9 + i;
            unsigned pp = u.svcv[pos4*144 + hh4*36 + s];
            svs += bflo(pp); cvs += bfhi(pp);
            int kk = s >> 2, h2 = s & 3;
            int nbr = (py + kk/3)*5 + (px + kk%3);
            mass += sact[nbr*4 + h2];
        }
        svs += __shfl_xor(svs, 1); cvs += __shfl_xor(cvs, 1); mass += __shfl_xor(mass, 1);
        svs += __shfl_xor(svs, 2); cvs += __shfl_xor(cvs, 2); mass += __shfl_xor(mass, 2);
        if (qq == 0) {
            mass = fmaxf(mass, 1e-6f);
            const float support  = svs / mass;
            const float conflict = cvs / mass;
            const int bph = (b*PPOS + (y0 + py)*SIDE + x0 + px)*NHYP + hh4;
            const float pd = drive[bph]  + support;
            const float pr = resist[bph] + conflict;
            float e = fminf(fmaxf(pd - pr + cst[WS_SC+2], -3.f), 3.f);
            const float a = 1.f / (1.f + expf(-e));
            out[0*NOUT + bph] = support;
            out[1*NOUT + bph] = conflict;
            out[2*NOUT + bph] = pd;
            out[3*NOUT + bph] = pr;
            out[4*NOUT + bph] = e;
            out[5*NOUT + bph] = a;
            out[6*NOUT + bph] = mass;
            bl = a;
            en = -(a*logf(a + 1e-8f) + (1.f - a)*logf(1.f - a + 1e-8f));
            ar = (a > 0.5f) ? 1.f : 0.f;
        }
    }
    if (tid < 128) {   // waves 0,1 fully active: safe shuffles; lanes>=96 carry zeros
        #pragma unroll
        for (int off = 32; off > 0; off >>= 1) {
            bl += __shfl_down(bl, off); en += __shfl_down(en, off); ar += __shfl_down(ar, off);
        }
        if ((tid & 63) == 0) {
            sdot[(tid >> 6)*4 + 0] = bl;
            sdot[(tid >> 6)*4 + 1] = en;
            sdot[(tid >> 6)*4 + 2] = ar;
        }
    }
    __syncthreads();
    if (tid == 0) {
        part[blk]          = sdot[0] + sdot[4];
        part[NBLK + blk]   = sdot[1] + sdot[5];
        part[2*NBLK + blk] = sdot[2] + sdot[6];
    }
}

// ---------------- final: reduce per-block partials ----------------
__global__ __launch_bounds__(256) void eml_final(const float* __restrict__ part, float* __restrict__ out3)
{
    __shared__ float red[4*3];
    float bl = 0.f, en = 0.f, ar = 0.f;
    for (int i = threadIdx.x; i < NBLK; i += 256) {
        bl += part[i];
        en += part[NBLK + i];
        ar += part[2*NBLK + i];
    }
    #pragma unroll
    for (int off = 32; off > 0; off >>= 1) {
        bl += __shfl_down(bl, off); en += __shfl_down(en, off); ar += __shfl_down(ar, off);
    }
    const int lane = threadIdx.x & 63, wid = threadIdx.x >> 6;
    if (lane == 0) { red[wid*3] = bl; red[wid*3+1] = en; red[wid*3+2] = ar; }
    __syncthreads();
    if (threadIdx.x == 0) {
        float b2 = 0.f, e2 = 0.f, a2 = 0.f;
        for (int w = 0; w < 4; ++w) { b2 += red[w*3]; e2 += red[w*3+1]; a2 += red[w*3+2]; }
        const float inv = 1.0f / (float)NOUT;
        out3[0] = b2*inv; out3[1] = e2*inv; out3[2] = a2*inv;
    }
}

extern "C" void kernel_launch(void* const* d_in, const int* in_sizes, int n_in,
                              void* d_out, int out_size, void* d_ws, size_t ws_size,
                              hipStream_t stream)
{
    (void)in_sizes; (void)n_in; (void)out_size; (void)ws_size;
    const float* hs    = (const float*)d_in[0];
    const float* act   = (const float*)d_in[1];
    const float* drv   = (const float*)d_in[2];
    const float* res   = (const float*)d_in[3];
    const float* rel   = (const float*)d_in[4];
    const float* lnw   = (const float*)d_in[5];
    const float* lnb   = (const float*)d_in[6];
    const float* sw1   = (const float*)d_in[7];
    const float* sb1   = (const float*)d_in[8];
    const float* sw2   = (const float*)d_in[9];
    const float* sb2   = (const float*)d_in[10];
    const float* cw1   = (const float*)d_in[11];
    const float* cb1   = (const float*)d_in[12];
    const float* cw2   = (const float*)d_in[13];
    const float* cb2   = (const float*)d_in[14];
    const float* ebias = (const float*)d_in[15];
    float* out = (float*)d_out;
    float* ws  = (float*)d_ws;

    eml_fold<<<dim3(11), dim3(512), 0, stream>>>(
        rel, lnw, lnb, sw1, sb1, sw2, sb2, cw1, cb1, cw2, cb2, ebias, ws);
    eml_main<<<dim3(NBLK), dim3(THREADS), 0, stream>>>(
        hs, act, drv, res, out, ws, ws + WS_PART);
    eml_final<<<dim3(1), dim3(256), 0, stream>>>(ws + WS_PART, out + 7*NOUT);
}